// Round 18
// baseline (543.102 us; speedup 1.0000x reference)
//
#include <hip/hip_runtime.h>
#include <hip/hip_bf16.h>

#define D 64
#define CAP 32      // slots per node = one 64B line (row == line)
#define OVF_CAP 16384
#define NSHARD 8    // dst shards, bound to XCDs via blockIdx&7 heuristic
#define COOP_BLOCKS 1024   // 4 blocks/CU x 256 CUs -> co-resident by launch_bounds

__device__ __forceinline__ float bf2f(unsigned short u) {
    return __uint_as_float((unsigned int)u << 16);
}
__device__ __forceinline__ unsigned short f2bf(float f) {
    unsigned int u = __float_as_uint(f);
    unsigned int r = (u + 0x7fffu + ((u >> 16) & 1u)) >> 16;   // RNE
    return (unsigned short)r;
}

// Manual grid barrier (what cg::grid_group::sync compiles to, minus the
// launch API that failed in r17). bar must be zeroed before launch.
// __threadfence = agent-scope fence -> handles cross-XCD L2 visibility (G16).
__device__ __forceinline__ void grid_sync_manual(unsigned int* bar, unsigned int nb) {
    __syncthreads();
    if (threadIdx.x == 0) {
        __threadfence();                     // release
        atomicAdd(bar, 1u);                  // device-scope arrival
        while (__hip_atomic_load(bar, __ATOMIC_RELAXED,
                                 __HIP_MEMORY_SCOPE_AGENT) < nb) {
            __builtin_amdgcn_s_sleep(8);
        }
        __threadfence();                     // acquire
    }
    __syncthreads();
}

// ---------- Single fused kernel: mlp -> append -> gather, 2 manual grid syncs ----------
__global__ __launch_bounds__(256, 4) void fused_all_kernel(
    const float* __restrict__ x, const float* __restrict__ W,
    const float* __restrict__ b, const int* __restrict__ src,
    const int* __restrict__ dst, unsigned short* __restrict__ m,
    int* __restrict__ cnt, unsigned short* __restrict__ slots,
    int* __restrict__ ovf_cnt, unsigned int* __restrict__ ovf,
    unsigned int* __restrict__ bar, float* __restrict__ out,
    int n_nodes, int n_edges) {
    const int tid = threadIdx.x;
    const int nb = gridDim.x;
    const int lane = tid & 63;

    // ---- Phase 0+1: zero cnt/ovf, node MLP (m rows = 128 B bf16) ----
    for (int i = blockIdx.x * 256 + tid; i < n_nodes; i += nb * 256) cnt[i] = 0;
    if (blockIdx.x == 0 && tid == 0) *ovf_cnt = 0;
    {
        float w[D];
        #pragma unroll
        for (int k = 0; k < D; ++k) w[k] = W[k * D + lane];
        const float bias = b[lane];
        const int wave = (blockIdx.x * 256 + tid) >> 6;
        const int nwaves = (nb * 256) >> 6;
        for (int row = wave; row < n_nodes; row += nwaves) {
            const float4* xr = (const float4*)(x + (size_t)row * D);
            float acc = bias;
            #pragma unroll
            for (int kk = 0; kk < D / 4; ++kk) {
                float4 xv = xr[kk];   // wave-uniform address -> broadcast
                acc = fmaf(xv.x, w[4 * kk + 0], acc);
                acc = fmaf(xv.y, w[4 * kk + 1], acc);
                acc = fmaf(xv.z, w[4 * kk + 2], acc);
                acc = fmaf(xv.w, w[4 * kk + 3], acc);
            }
            m[(size_t)row * D + lane] = f2bf(fmaxf(acc, 0.0f));
        }
    }
    grid_sync_manual(&bar[0], nb);

    // ---- Phase 2: XCD-sharded append (r12 form; 1024 blocks = 128/shard) ----
    {
        const int shard = blockIdx.x & (NSHARD - 1);
        const int p = blockIdx.x >> 3;
        const int bps = nb >> 3;
        const int chunk = (n_edges + bps - 1) / bps;
        const int beg = p * chunk;
        const int end = min(beg + chunk, n_edges);
        for (int e = beg + tid; e < end; e += 256) {
            int d = dst[e];                  // coalesced; L3-served (8x redundant)
            if ((d & (NSHARD - 1)) != shard) continue;
            int s = src[e];
            int pos = atomicAdd(&cnt[d], 1); // memory-side atomic
            if (pos < CAP) {
                slots[(size_t)d * CAP + pos] = (unsigned short)s;
            } else {                         // ~4 nodes expected (P(deg>32)~8e-5)
                int op = atomicAdd(ovf_cnt, 1);
                if (op < OVF_CAP)
                    ovf[op] = ((unsigned int)d << 16) | (unsigned int)s;
            }
        }
    }
    grid_sync_manual(&bar[1], nb);

    // ---- Phase 3: gather (r15 form: scalar slot row, saddr loads, XCD map) ----
    {
        const int xcd = blockIdx.x & 7;
        const int ngroups = (n_nodes + 31) / 32;
        const int gstride = nb >> 3;
        for (int g = blockIdx.x >> 3; g < ngroups; g += gstride) {
            int node = g * 32 + ((tid >> 6) << 3) + xcd;  // node&7 == blockIdx&7
            if (node >= n_nodes) continue;                 // wave-uniform
            node = __builtin_amdgcn_readfirstlane(node);

            const int c = cnt[node];                       // scalar load
            const int cc = min(c, CAP);
            const unsigned int* __restrict__ row =
                (const unsigned int*)(slots + (size_t)node * CAP);

            float acc = 0.0f;
            int k = 0;
            for (; k + 16 <= cc; k += 16) {
                unsigned int p[8];
                #pragma unroll
                for (int i = 0; i < 8; ++i) p[i] = row[(k >> 1) + i];
                float v[16];
                #pragma unroll
                for (int i = 0; i < 8; ++i) {   // 16 saddr loads in flight
                    const unsigned short* ba = m + (size_t)(p[i] & 0xFFFFu) * D;
                    const unsigned short* bb = m + (size_t)(p[i] >> 16) * D;
                    v[2 * i + 0] = bf2f(ba[lane]);
                    v[2 * i + 1] = bf2f(bb[lane]);
                }
                float t0 = ((v[0] + v[1]) + (v[2] + v[3])) + ((v[4] + v[5]) + (v[6] + v[7]));
                float t1 = ((v[8] + v[9]) + (v[10] + v[11])) + ((v[12] + v[13]) + (v[14] + v[15]));
                acc += t0 + t1;
            }
            for (; k + 4 <= cc; k += 4) {
                unsigned int p0 = row[(k >> 1) + 0];
                unsigned int p1 = row[(k >> 1) + 1];
                const unsigned short* b0 = m + (size_t)(p0 & 0xFFFFu) * D;
                const unsigned short* b1 = m + (size_t)(p0 >> 16) * D;
                const unsigned short* b2 = m + (size_t)(p1 & 0xFFFFu) * D;
                const unsigned short* b3 = m + (size_t)(p1 >> 16) * D;
                float v0 = bf2f(b0[lane]);
                float v1 = bf2f(b1[lane]);
                float v2 = bf2f(b2[lane]);
                float v3 = bf2f(b3[lane]);
                acc += (v0 + v1) + (v2 + v3);
            }
            for (; k < cc; ++k) {
                unsigned int p = row[k >> 1];
                unsigned int s = (k & 1) ? (p >> 16) : (p & 0xFFFFu);
                acc += bf2f(m[(size_t)s * D + lane]);
            }
            if (c > CAP) {                    // rare: scan tiny ovf list
                int oc = min(*(volatile int*)ovf_cnt, OVF_CAP);
                for (int i = 0; i < oc; ++i) {
                    unsigned int e = ovf[i];
                    if ((int)(e >> 16) == node)
                        acc += bf2f(m[(size_t)(e & 0xFFFFu) * D + lane]);
                }
            }
            out[(size_t)node * D + lane] = acc;   // coalesced 256B/wave
        }
    }
}

// ---------- Fallback path kernels (ws too small / nodes don't fit u16) ----------
__global__ __launch_bounds__(256) void node_mlp_kernel(
    const float* __restrict__ x, const float* __restrict__ W,
    const float* __restrict__ b, unsigned short* __restrict__ m, int n_nodes) {
    const int lane = threadIdx.x & 63;
    float w[D];
    #pragma unroll
    for (int k = 0; k < D; ++k) w[k] = W[k * D + lane];
    const float bias = b[lane];
    const int wave = (blockIdx.x * blockDim.x + threadIdx.x) >> 6;
    const int nwaves = (gridDim.x * blockDim.x) >> 6;
    for (int row = wave; row < n_nodes; row += nwaves) {
        const float4* xr = (const float4*)(x + (size_t)row * D);
        float acc = bias;
        #pragma unroll
        for (int kk = 0; kk < D / 4; ++kk) {
            float4 xv = xr[kk];
            acc = fmaf(xv.x, w[4 * kk + 0], acc);
            acc = fmaf(xv.y, w[4 * kk + 1], acc);
            acc = fmaf(xv.z, w[4 * kk + 2], acc);
            acc = fmaf(xv.w, w[4 * kk + 3], acc);
        }
        m[(size_t)row * D + lane] = f2bf(fmaxf(acc, 0.0f));
    }
}

__global__ __launch_bounds__(256) void edge_scatter_kernel(
    const int* __restrict__ src, const int* __restrict__ dst,
    const unsigned short* __restrict__ m, float* __restrict__ out, int n_edges) {
    long long t = (long long)blockIdx.x * blockDim.x + threadIdx.x;
    int e = (int)(t >> 4);
    if (e >= n_edges) return;
    int c = (int)(t & 15) << 2;
    int s = src[e];
    int d = dst[e];
    const ushort4 v = *(const ushort4*)(m + (size_t)s * D + c);
    float* o = out + (size_t)d * D + c;
    atomicAdd(o + 0, bf2f(v.x));
    atomicAdd(o + 1, bf2f(v.y));
    atomicAdd(o + 2, bf2f(v.z));
    atomicAdd(o + 3, bf2f(v.w));
}

static inline size_t align_up(size_t v, size_t a) { return (v + a - 1) & ~(a - 1); }

extern "C" void kernel_launch(void* const* d_in, const int* in_sizes, int n_in,
                              void* d_out, int out_size, void* d_ws, size_t ws_size,
                              hipStream_t stream) {
    const float* x = (const float*)d_in[0];
    const int* edge_index = (const int*)d_in[1];   // int32 per harness contract
    const float* W = (const float*)d_in[2];
    const float* b = (const float*)d_in[3];
    float* out = (float*)d_out;

    const int n_nodes = in_sizes[0] / D;        // 50000
    const int n_edges = in_sizes[1] / 2;        // 800000
    const int* src = edge_index;                // row 0 (j, gather)
    const int* dst = edge_index + n_edges;      // row 1 (i, scatter)

    // Workspace layout (~10 MB total)
    size_t off = 0;
    unsigned short* m = (unsigned short*)((char*)d_ws + off);
    off = align_up(off + (size_t)n_nodes * D * sizeof(unsigned short), 256);
    int* cnt = (int*)((char*)d_ws + off);
    off = align_up(off + (size_t)n_nodes * sizeof(int), 256);
    unsigned short* slots = (unsigned short*)((char*)d_ws + off);
    off = align_up(off + (size_t)n_nodes * CAP * sizeof(unsigned short), 256);
    int* ovf_cnt = (int*)((char*)d_ws + off);
    off = align_up(off + sizeof(int), 256);
    unsigned int* ovf = (unsigned int*)((char*)d_ws + off);
    off = align_up(off + (size_t)OVF_CAP * sizeof(unsigned int), 256);
    unsigned int* bar = (unsigned int*)((char*)d_ws + off);
    off = align_up(off + 2 * sizeof(unsigned int), 256);
    const size_t needed = off;

    if (ws_size >= needed && n_nodes <= 65536) {
        hipMemsetAsync(bar, 0, 2 * sizeof(unsigned int), stream);  // zero barriers
        fused_all_kernel<<<COOP_BLOCKS, 256, 0, stream>>>(
            x, W, b, src, dst, m, cnt, slots, ovf_cnt, ovf, bar, out,
            n_nodes, n_edges);
    } else {
        node_mlp_kernel<<<512, 256, 0, stream>>>(x, W, b, m, n_nodes);
        hipMemsetAsync(d_out, 0, (size_t)out_size * sizeof(float), stream);
        long long total_threads = (long long)n_edges * 16;
        int scat_blocks = (int)((total_threads + 255) / 256);
        edge_scatter_kernel<<<scat_blocks, 256, 0, stream>>>(src, dst, m, out, n_edges);
    }
}

// Round 19
// 155.815 us; speedup vs baseline: 3.4856x; 3.4856x over previous
//
#include <hip/hip_runtime.h>
#include <hip/hip_bf16.h>

#define D 64
#define CAP 32      // slots per node = one 64B line (row == line)
#define OVF_CAP 16384
#define NSHARD 8    // dst shards, bound to XCDs via blockIdx&7 heuristic

__device__ __forceinline__ float bf2f(unsigned short u) {
    return __uint_as_float((unsigned int)u << 16);
}
__device__ __forceinline__ unsigned short f2bf(float f) {
    unsigned int u = __float_as_uint(f);
    unsigned int r = (u + 0x7fffu + ((u >> 16) & 1u)) >> 16;   // RNE
    return (unsigned short)r;
}

// ---------- Kernel 1: m[n][:] = bf16(relu(x @ W + b)) (unified 128B rows); zero cnt/ovf ----------
__global__ __launch_bounds__(256) void node_mlp_kernel(
    const float* __restrict__ x, const float* __restrict__ W,
    const float* __restrict__ b, unsigned short* __restrict__ m,
    int* __restrict__ cnt, int* __restrict__ ovf_cnt, int n_nodes) {
    for (int i = blockIdx.x * blockDim.x + threadIdx.x; i < n_nodes;
         i += gridDim.x * blockDim.x) cnt[i] = 0;
    if (blockIdx.x == 0 && threadIdx.x == 0) *ovf_cnt = 0;

    const int lane = threadIdx.x & 63;
    float w[D];
    #pragma unroll
    for (int k = 0; k < D; ++k) w[k] = W[k * D + lane];
    const float bias = b[lane];

    const int wave = (blockIdx.x * blockDim.x + threadIdx.x) >> 6;
    const int nwaves = (gridDim.x * blockDim.x) >> 6;

    for (int row = wave; row < n_nodes; row += nwaves) {
        const float4* xr = (const float4*)(x + (size_t)row * D);
        float acc = bias;
        #pragma unroll
        for (int kk = 0; kk < D / 4; ++kk) {
            float4 xv = xr[kk];   // wave-uniform address -> broadcast, 1 request
            acc = fmaf(xv.x, w[4 * kk + 0], acc);
            acc = fmaf(xv.y, w[4 * kk + 1], acc);
            acc = fmaf(xv.z, w[4 * kk + 2], acc);
            acc = fmaf(xv.w, w[4 * kk + 3], acc);
        }
        m[(size_t)row * D + lane] = f2bf(fmaxf(acc, 0.0f));
    }
}

// ---------- Kernel 2: XCD-sharded append (r12 form) ----------
// Block group k (blockIdx&7==k) handles only dst with (d&7)==k; co-resident
// blocks share an XCD under round-robin dispatch, so each slot line is
// written by one L2 and merges into a single writeback (round 12 win).
// NOTE r18: do NOT fuse phases into one kernel — the required agent-scope
// fences invalidate per-XCD L2s and cost 3x (FETCH 50->287 MB).
__global__ __launch_bounds__(256) void append_kernel(
    const int* __restrict__ src, const int* __restrict__ dst,
    int* __restrict__ cnt, unsigned short* __restrict__ slots,
    int* __restrict__ ovf_cnt, unsigned int* __restrict__ ovf,
    int n_edges, int blocks_per_shard) {
    const int shard = blockIdx.x & (NSHARD - 1);
    const int p = blockIdx.x >> 3;          // rank within shard group
    const int chunk = (n_edges + blocks_per_shard - 1) / blocks_per_shard;
    const int beg = p * chunk;
    const int end = min(beg + chunk, n_edges);

    for (int e = beg + (int)threadIdx.x; e < end; e += 256) {
        int d = dst[e];                      // coalesced; L3-served (8x redundant)
        if ((d & (NSHARD - 1)) != shard) continue;
        int s = src[e];
        int pos = atomicAdd(&cnt[d], 1);     // memory-side atomic
        if (pos < CAP) {
            slots[(size_t)d * CAP + pos] = (unsigned short)s;
        } else {                             // ~4 nodes expected (P(deg>32)~8e-5)
            int op = atomicAdd(ovf_cnt, 1);
            if (op < OVF_CAP)
                ovf[op] = ((unsigned int)d << 16) | (unsigned int)s;
        }
    }
}

// ---------- Kernel 3: gather — one wave/node, fully scalar addressing (r15 win) ----------
__global__ __launch_bounds__(256) void gather_kernel(
    const unsigned short* __restrict__ slots, const int* __restrict__ cnt,
    const unsigned short* __restrict__ m,
    const int* __restrict__ ovf_cnt, const unsigned int* __restrict__ ovf,
    float* __restrict__ out, int n_nodes) {
    const int grp = blockIdx.x >> 3;          // 8-block group covers 32 nodes
    const int xcd = blockIdx.x & 7;
    int node = grp * 32 + ((threadIdx.x >> 6) << 3) + xcd;  // node&7 == blockIdx&7
    if (node >= n_nodes) return;              // wave-uniform branch
    node = __builtin_amdgcn_readfirstlane(node);

    const int lane = threadIdx.x & 63;

    const int c = cnt[node];                  // scalar load
    const int cc = min(c, CAP);
    const unsigned int* __restrict__ row =
        (const unsigned int*)(slots + (size_t)node * CAP);  // scalar base

    float acc = 0.0f;
    int k = 0;
    for (; k + 16 <= cc; k += 16) {
        unsigned int p[8];
        #pragma unroll
        for (int i = 0; i < 8; ++i) p[i] = row[(k >> 1) + i];  // s_load x8
        float v[16];
        #pragma unroll
        for (int i = 0; i < 8; ++i) {         // 16 saddr loads in flight
            const unsigned short* ba = m + (size_t)(p[i] & 0xFFFFu) * D; // SGPR base
            const unsigned short* bb = m + (size_t)(p[i] >> 16) * D;     // SGPR base
            v[2 * i + 0] = bf2f(ba[lane]);    // global_load_ushort v, vlane2, s[..]
            v[2 * i + 1] = bf2f(bb[lane]);
        }
        float t0 = ((v[0] + v[1]) + (v[2] + v[3])) + ((v[4] + v[5]) + (v[6] + v[7]));
        float t1 = ((v[8] + v[9]) + (v[10] + v[11])) + ((v[12] + v[13]) + (v[14] + v[15]));
        acc += t0 + t1;
    }
    for (; k + 4 <= cc; k += 4) {
        unsigned int p0 = row[(k >> 1) + 0];
        unsigned int p1 = row[(k >> 1) + 1];
        const unsigned short* b0 = m + (size_t)(p0 & 0xFFFFu) * D;
        const unsigned short* b1 = m + (size_t)(p0 >> 16) * D;
        const unsigned short* b2 = m + (size_t)(p1 & 0xFFFFu) * D;
        const unsigned short* b3 = m + (size_t)(p1 >> 16) * D;
        float v0 = bf2f(b0[lane]);
        float v1 = bf2f(b1[lane]);
        float v2 = bf2f(b2[lane]);
        float v3 = bf2f(b3[lane]);
        acc += (v0 + v1) + (v2 + v3);
    }
    for (; k < cc; ++k) {
        unsigned int p = row[k >> 1];
        unsigned int s = (k & 1) ? (p >> 16) : (p & 0xFFFFu);
        acc += bf2f(m[(size_t)s * D + lane]);
    }
    if (c > CAP) {                            // rare: scan tiny ovf list (uniform)
        int oc = min(*ovf_cnt, OVF_CAP);
        for (int i = 0; i < oc; ++i) {
            unsigned int e = ovf[i];
            if ((int)(e >> 16) == node)
                acc += bf2f(m[(size_t)(e & 0xFFFFu) * D + lane]);
        }
    }
    out[(size_t)node * D + lane] = acc;       // fully coalesced 256B/wave
}

// ---------- Fallback: atomic scatter (unified m) ----------
__global__ __launch_bounds__(256) void edge_scatter_kernel(
    const int* __restrict__ src, const int* __restrict__ dst,
    const unsigned short* __restrict__ m, float* __restrict__ out, int n_edges) {
    long long t = (long long)blockIdx.x * blockDim.x + threadIdx.x;
    int e = (int)(t >> 4);
    if (e >= n_edges) return;
    int c = (int)(t & 15) << 2;
    int s = src[e];
    int d = dst[e];
    const ushort4 v = *(const ushort4*)(m + (size_t)s * D + c);
    float* o = out + (size_t)d * D + c;
    atomicAdd(o + 0, bf2f(v.x));
    atomicAdd(o + 1, bf2f(v.y));
    atomicAdd(o + 2, bf2f(v.z));
    atomicAdd(o + 3, bf2f(v.w));
}

static inline size_t align_up(size_t v, size_t a) { return (v + a - 1) & ~(a - 1); }

extern "C" void kernel_launch(void* const* d_in, const int* in_sizes, int n_in,
                              void* d_out, int out_size, void* d_ws, size_t ws_size,
                              hipStream_t stream) {
    const float* x = (const float*)d_in[0];
    const int* edge_index = (const int*)d_in[1];   // int32 per harness contract
    const float* W = (const float*)d_in[2];
    const float* b = (const float*)d_in[3];
    float* out = (float*)d_out;

    const int n_nodes = in_sizes[0] / D;        // 50000
    const int n_edges = in_sizes[1] / 2;        // 800000
    const int* src = edge_index;                // row 0 (j, gather)
    const int* dst = edge_index + n_edges;      // row 1 (i, scatter)

    // Workspace layout (~10 MB total)
    size_t off = 0;
    unsigned short* m = (unsigned short*)((char*)d_ws + off);
    off = align_up(off + (size_t)n_nodes * D * sizeof(unsigned short), 256);
    int* cnt = (int*)((char*)d_ws + off);
    off = align_up(off + (size_t)n_nodes * sizeof(int), 256);
    unsigned short* slots = (unsigned short*)((char*)d_ws + off);
    off = align_up(off + (size_t)n_nodes * CAP * sizeof(unsigned short), 256);
    int* ovf_cnt = (int*)((char*)d_ws + off);
    off = align_up(off + sizeof(int), 256);
    unsigned int* ovf = (unsigned int*)((char*)d_ws + off);
    off = align_up(off + (size_t)OVF_CAP * sizeof(unsigned int), 256);
    const size_t needed = off;

    // Node MLP (+ fused cnt/ovf zeroing): 512 blocks -> 8 waves/CU
    node_mlp_kernel<<<512, 256, 0, stream>>>(x, W, b, m, cnt, ovf_cnt, n_nodes);

    if (ws_size >= needed && n_nodes <= 65536) {
        const int blocks_per_shard = 320;           // 2560 blocks (r16 best)
        append_kernel<<<blocks_per_shard * NSHARD, 256, 0, stream>>>(
            src, dst, cnt, slots, ovf_cnt, ovf, n_edges, blocks_per_shard);
        const int ngroups = (n_nodes + 31) / 32;    // 8 blocks per 32-node group
        gather_kernel<<<ngroups * 8, 256, 0, stream>>>(
            slots, cnt, m, ovf_cnt, ovf, out, n_nodes);
    } else {
        hipMemsetAsync(d_out, 0, (size_t)out_size * sizeof(float), stream);
        long long total_threads = (long long)n_edges * 16;
        int scat_blocks = (int)((total_threads + 255) / 256);
        edge_scatter_kernel<<<scat_blocks, 256, 0, stream>>>(src, dst, m, out, n_edges);
    }
}